// Round 4
// baseline (1244.287 us; speedup 1.0000x reference)
//
#include <hip/hip_runtime.h>
#include <cstdint>
#include <cstddef>

// ---------------------------------------------------------------------------
// PiFormerFFN: out = gelu_q(x @ W1^T) @ W2^T
// R3 changes vs R2:
//   - Fragment-ordered LDS layout: global_load_lds source addressing is
//     per-lane arbitrary, so stage tiles in EXACT MFMA-fragment order.
//     Every ds_read_b128 is then "base + lane*16" (lane-consecutive, <=2-way
//     bank aliasing = free). Kills the 3.36e7 conflict cycles R2 showed and
//     collapses LDS read addressing to one base + immediate offsets.
// ---------------------------------------------------------------------------

typedef __bf16 bf16_t;
typedef bf16_t bf16x8 __attribute__((ext_vector_type(8)));
typedef bf16_t bf16x4 __attribute__((ext_vector_type(4)));
typedef float  floatx16 __attribute__((ext_vector_type(16)));

#define AS1 __attribute__((address_space(1)))
#define AS3 __attribute__((address_space(3)))

__device__ __forceinline__ void async_cp16(const void* g, void* l) {
    __builtin_amdgcn_global_load_lds((const AS1 void*)g, (AS3 void*)l, 16, 0, 0);
}

// tanh-approx gelu: gelu = x * (1 - 1/(1+e^{2u})), u = k0*(x + k1*x^3)
__device__ __forceinline__ float gelu_fast(float x) {
    const float C0 = 1.5957691216057308f;   // 2*sqrt(2/pi)
    const float C1 = 0.0713548163f;         // C0 * 0.044715
    float u2 = x * fmaf(C1, x * x, C0);
    float e  = __expf(u2);
    float r  = __builtin_amdgcn_rcpf(1.0f + e);
    return x * (1.0f - r);
}

// fp32 -> bf16 (RNE), 4 elems/thread
__global__ __launch_bounds__(256)
void cvt_f32_to_bf16(const float4* __restrict__ in, bf16x4* __restrict__ out, int n4)
{
    int i = blockIdx.x * blockDim.x + threadIdx.x;
    if (i >= n4) return;
    float4 v = in[i];
    bf16x4 o;
    o[0] = (bf16_t)v.x; o[1] = (bf16_t)v.y; o[2] = (bf16_t)v.z; o[3] = (bf16_t)v.w;
    out[i] = o;
}

// C[M,N] = A[M,K] * B[N,K]^T  (both K-contiguous; bf16 in, fp32 acc)
// 128x128 block tile, 4 waves (2x2), each wave 2x2 MFMA 32x32x16 tiles, BK=32.
//
// LDS fragment order: 16B chunk index c in [0,512) holds
//   g = c>>6 (frag block: rb = g>>1 in [0,4) = 32-row block, ks = g&1 k-step)
//   lane = c&63:  row = rb*32 + (lane&31),  kc = 2*ks + (lane>>5)
// so frag-block fb at byte offset fb*1024, lane reads fb*1024 + lane*16.
template<bool ACT, typename OutT, bool XCDSWZ>
__global__ __launch_bounds__(256)
void gemm_bt(const bf16_t* __restrict__ A, const bf16_t* __restrict__ B,
             OutT* __restrict__ C, int M, int N, int K, int nbx, int nby)
{
    __shared__ __align__(16) bf16_t As[128 * 32];
    __shared__ __align__(16) bf16_t Bs[128 * 32];

    int bx, by;
    if (XCDSWZ) {
        // L%8 = XCD heuristic; each XCD gets nby/8 contiguous row-panels.
        const int L   = blockIdx.x;
        const int xcd = L & 7;
        const int j   = L >> 3;
        const int jy  = j / nbx;
        by = xcd * (nby >> 3) + jy;
        bx = j - jy * nbx;
    } else {
        bx = blockIdx.x; by = blockIdx.y;
    }

    const int tid  = threadIdx.x;
    const int lane = tid & 63;
    const int wave = tid >> 6;
    const int wr = (wave >> 1) * 64;        // wave row offset in 128-tile
    const int wc = (wave & 1) * 64;         // wave col offset
    const int brow = by * 128;
    const int bcol = bx * 128;

    const int l31 = lane & 31;              // MFMA row/col within 32
    const int lh  = lane >> 5;              // half-wave (k-chunk select)

    floatx16 acc[2][2];
    #pragma unroll
    for (int i = 0; i < 2; ++i)
      #pragma unroll
      for (int j = 0; j < 2; ++j)
        acc[i][j] = (floatx16)0.0f;

    // Staging: thread t fills chunks c0=t, c1=t+256 (dest = base + lane*16,
    // wave-uniform constraint satisfied). Source = fragment-order mapping.
    const int c0 = tid, c1 = tid + 256;
    const int g0 = c0 >> 6, g1 = c1 >> 6;
    const int r0 = (g0 >> 1) * 32 + (c0 & 31);
    const int o0 = (2 * (g0 & 1) + ((c0 >> 5) & 1)) * 8;
    const int r1 = (g1 >> 1) * 32 + (c1 & 31);
    const int o1 = (2 * (g1 & 1) + ((c1 >> 5) & 1)) * 8;

    const bf16_t* Arow0 = A + (size_t)(brow + r0) * K + o0;
    const bf16_t* Arow1 = A + (size_t)(brow + r1) * K + o1;
    const bf16_t* Brow0 = B + (size_t)(bcol + r0) * K + o0;
    const bf16_t* Brow1 = B + (size_t)(bcol + r1) * K + o1;

    const int fra = (wr >> 5) * 2;          // wave's first A frag-block
    const int frb = (wc >> 5) * 2;          // wave's first B frag-block

    for (int kt = 0; kt < K; kt += 32) {
        async_cp16(Arow0 + kt, (char*)As + c0 * 16);
        async_cp16(Arow1 + kt, (char*)As + c1 * 16);
        async_cp16(Brow0 + kt, (char*)Bs + c0 * 16);
        async_cp16(Brow1 + kt, (char*)Bs + c1 * 16);
        __syncthreads();

        // frag block fb = rb*2 + ks at elements [fb*512, +512); lane slice *8.
        bf16x8 af[2][2], bfr[2][2];          // [tile i][ks]
        #pragma unroll
        for (int i = 0; i < 2; ++i) {
          #pragma unroll
          for (int ks = 0; ks < 2; ++ks) {
            af[i][ks]  = *(const bf16x8*)(As + (fra + i * 2 + ks) * 512 + lane * 8);
            bfr[i][ks] = *(const bf16x8*)(Bs + (frb + i * 2 + ks) * 512 + lane * 8);
          }
        }
        #pragma unroll
        for (int ks = 0; ks < 2; ++ks)
          #pragma unroll
          for (int mi = 0; mi < 2; ++mi)
            #pragma unroll
            for (int ni = 0; ni < 2; ++ni)
              acc[mi][ni] = __builtin_amdgcn_mfma_f32_32x32x16_bf16(
                  af[mi][ks], bfr[ni][ks], acc[mi][ni], 0, 0, 0);
        __syncthreads();
    }

    // Epilogue. 32x32 C/D layout: col = lane&31,
    // row = (reg&3) + 8*(reg>>2) + 4*(lane>>5).
    #pragma unroll
    for (int mi = 0; mi < 2; ++mi) {
      #pragma unroll
      for (int ni = 0; ni < 2; ++ni) {
        const int col = bcol + wc + ni * 32 + l31;
        #pragma unroll
        for (int r = 0; r < 16; ++r) {
          const int row = brow + wr + mi * 32 + (r & 3) + 8 * (r >> 2) + 4 * lh;
          float h = acc[mi][ni][r];
          if (ACT) {
            float q = rintf(h * 10.0f);          // round half-to-even
            q = fminf(fmaxf(q, -32768.0f), 32767.0f);
            h = gelu_fast(q * 0.1f);
          }
          C[(size_t)row * N + col] = (OutT)h;
        }
      }
    }
}

extern "C" void kernel_launch(void* const* d_in, const int* in_sizes, int n_in,
                              void* d_out, int out_size, void* d_ws, size_t ws_size,
                              hipStream_t stream)
{
    const int M  = 8192;   // BATCH*SEQ
    const int DM = 2048;   // d_model
    const int DF = 8192;   // d_ff

    const float* x  = (const float*)d_in[0];
    const float* W1 = (const float*)d_in[1];
    const float* W2 = (const float*)d_in[2];
    float* out = (float*)d_out;

    bf16_t* xb  = (bf16_t*)d_ws;
    bf16_t* w1b = xb  + (size_t)M  * DM;
    bf16_t* w2b = w1b + (size_t)DF * DM;
    bf16_t* act = w2b + (size_t)DM * DF;

    {
        int n4 = (M * DM) / 4;
        cvt_f32_to_bf16<<<(n4 + 255) / 256, 256, 0, stream>>>((const float4*)x,  (bf16x4*)xb,  n4);
        n4 = (DF * DM) / 4;
        cvt_f32_to_bf16<<<(n4 + 255) / 256, 256, 0, stream>>>((const float4*)W1, (bf16x4*)w1b, n4);
        n4 = (DM * DF) / 4;
        cvt_f32_to_bf16<<<(n4 + 255) / 256, 256, 0, stream>>>((const float4*)W2, (bf16x4*)w2b, n4);
    }

    // GEMM1 + fused quant/gelu: act[M,DF] = gelu_q(xb @ w1b^T)
    gemm_bt<true, bf16_t, false>
        <<<dim3(DF / 128, M / 128), 256, 0, stream>>>(xb, w1b, act, M, DF, DM, 0, 0);
    // GEMM2: out[M,DM] = act @ w2b^T, XCD-grouped block order
    gemm_bt<false, float, true>
        <<<dim3((DM / 128) * (M / 128), 1), 256, 0, stream>>>(act, w2b, out, M, DM, DF, DM / 128, M / 128);
}

// Round 5
// 816.598 us; speedup vs baseline: 1.5237x; 1.5237x over previous
//
#include <hip/hip_runtime.h>
#include <cstdint>
#include <cstddef>

// ---------------------------------------------------------------------------
// PiFormerFFN: out = gelu_q(x @ W1^T) @ W2^T
// R4: pre-packed fragment-order operand layout.
//   R3 showed fragment-order LDS + identity copy scatters the GLOBAL side
//   (uncoalesced staging, latency-bound). Fix: pack operands in memory in
//   exact MFMA-fragment tile order, so staging is identity (wave reads 1KB
//   contiguous) AND ds_read_b128 is base+lane*16 (conflict-free).
//   - converters pack x/W1/W2 fp32 -> bf16 tile-major fragment order
//   - GEMM1 epilogue packs act via LDS (2 phases, XOR chunk swizzle)
//   - GEMM kernel: 128x128 tile, 4 waves, 2x2 of 32x32x16 MFMA, BK=32
// Packed layout for operand [R,K]: panel p = row/128, ktile t = k/32,
//   chunk c = (rb*2+ks)*64 + half*32 + rr  where row = p*128+rb*32+rr,
//   k = t*32 + ks*16 + half*8.  Chunk index = (p*(K/32)+t)*512 + c, 16B each.
// ---------------------------------------------------------------------------

typedef __bf16 bf16_t;
typedef bf16_t bf16x8 __attribute__((ext_vector_type(8)));
typedef float  floatx16 __attribute__((ext_vector_type(16)));

#define AS1 __attribute__((address_space(1)))
#define AS3 __attribute__((address_space(3)))

__device__ __forceinline__ void async_cp16(const void* g, void* l) {
    __builtin_amdgcn_global_load_lds((const AS1 void*)g, (AS3 void*)l, 16, 0, 0);
}

// tanh-approx gelu: gelu = x * (1 - 1/(1+e^{2u})), u = k0*(x + k1*x^3)
__device__ __forceinline__ float gelu_fast(float x) {
    const float C0 = 1.5957691216057308f;   // 2*sqrt(2/pi)
    const float C1 = 0.0713548163f;         // C0 * 0.044715
    float u2 = x * fmaf(C1, x * x, C0);
    float e  = __expf(u2);
    float r  = __builtin_amdgcn_rcpf(1.0f + e);
    return x * (1.0f - r);
}

// fp32 [R,K] -> bf16 packed fragment-order. One thread per 16B chunk.
// tshift = log2(K/32). Writes perfectly coalesced; reads consume whole 64B
// lines (lane l and l+32 read the two 32B halves of each row's 64B span).
__global__ __launch_bounds__(256)
void cvt_pack_bf16(const float* __restrict__ src, bf16_t* __restrict__ dst,
                   int K, int tshift)
{
    const size_t oc = (size_t)blockIdx.x * 256 + threadIdx.x;
    const int    c  = (int)(oc & 511);
    const size_t tl = oc >> 9;
    const int    t  = (int)(tl & ((1u << tshift) - 1));
    const size_t p  = tl >> tshift;
    const int g = c >> 6, lane = c & 63;
    const int rb = g >> 1, ks = g & 1, half = lane >> 5, rr = lane & 31;
    const size_t row = p * 128 + rb * 32 + rr;
    const int    k   = (t << 5) + ks * 16 + half * 8;
    const float* s = src + row * (size_t)K + k;
    float4 a = *(const float4*)s;
    float4 b = *(const float4*)(s + 4);
    bf16x8 o;
    o[0] = (bf16_t)a.x; o[1] = (bf16_t)a.y; o[2] = (bf16_t)a.z; o[3] = (bf16_t)a.w;
    o[4] = (bf16_t)b.x; o[5] = (bf16_t)b.y; o[6] = (bf16_t)b.z; o[7] = (bf16_t)b.w;
    *(bf16x8*)(dst + oc * 8) = o;
}

// C = A * B^T with A,B in packed fragment-order layout (see header comment).
// ACT=true: C is the packed-layout act buffer (bf16), fused quant+gelu, LDS
// re-pack epilogue. ACT=false: C is row-major fp32 [M,N].
template<bool ACT, typename OutT, bool XCDSWZ>
__global__ __launch_bounds__(256)
void gemm_bt(const bf16_t* __restrict__ A, const bf16_t* __restrict__ B,
             OutT* __restrict__ C, int M, int N, int K, int nbx, int nby)
{
    __shared__ __align__(16) bf16_t smem[2 * 128 * 32];   // As | Bs (16 KB)
    bf16_t* As = smem;
    bf16_t* Bs = smem + 128 * 32;

    int bx, by;
    if (XCDSWZ) {
        // L%8 = XCD heuristic; each XCD gets nby/8 contiguous row-panels.
        const int L   = blockIdx.x;
        const int xcd = L & 7;
        const int j   = L >> 3;
        const int jy  = j / nbx;
        by = xcd * (nby >> 3) + jy;
        bx = j - jy * nbx;
    } else {
        bx = blockIdx.x; by = blockIdx.y;
    }

    const int tid  = threadIdx.x;
    const int lane = tid & 63;
    const int wave = tid >> 6;
    const int wr = (wave >> 1) * 64;        // wave row offset in 128-tile
    const int wc = (wave & 1) * 64;         // wave col offset
    const int l31 = lane & 31;
    const int lh  = lane >> 5;

    floatx16 acc[2][2];
    #pragma unroll
    for (int i = 0; i < 2; ++i)
      #pragma unroll
      for (int j = 0; j < 2; ++j)
        acc[i][j] = (floatx16)0.0f;

    // Identity staging: thread t copies packed chunks t and t+256.
    const int c0 = tid, c1 = tid + 256;
    const bf16_t* Ap = A + (((size_t)by) << 7) * K;   // 128-row panel base
    const bf16_t* Bp = B + (((size_t)bx) << 7) * K;

    const int fra = (wr >> 5) * 2;          // wave's first A frag-block
    const int frb = (wc >> 5) * 2;          // wave's first B frag-block

    const int niter = K >> 5;
    for (int it = 0; it < niter; ++it) {
        const bf16_t* a_src = Ap + (size_t)it * 4096;  // 512 chunks * 8 elems
        const bf16_t* b_src = Bp + (size_t)it * 4096;
        async_cp16(a_src + c0 * 8, (char*)As + c0 * 16);
        async_cp16(a_src + c1 * 8, (char*)As + c1 * 16);
        async_cp16(b_src + c0 * 8, (char*)Bs + c0 * 16);
        async_cp16(b_src + c1 * 8, (char*)Bs + c1 * 16);
        __syncthreads();

        // frag block fb at elements [fb*512,+512); lane slice lane*8 (16B).
        bf16x8 af[2][2], bfr[2][2];          // [tile i][ks]
        #pragma unroll
        for (int i = 0; i < 2; ++i) {
          #pragma unroll
          for (int ks = 0; ks < 2; ++ks) {
            af[i][ks]  = *(const bf16x8*)(As + (fra + i * 2 + ks) * 512 + lane * 8);
            bfr[i][ks] = *(const bf16x8*)(Bs + (frb + i * 2 + ks) * 512 + lane * 8);
          }
        }
        #pragma unroll
        for (int ks = 0; ks < 2; ++ks)
          #pragma unroll
          for (int mi = 0; mi < 2; ++mi)
            #pragma unroll
            for (int ni = 0; ni < 2; ++ni)
              acc[mi][ni] = __builtin_amdgcn_mfma_f32_32x32x16_bf16(
                  af[mi][ks], bfr[ni][ks], acc[mi][ni], 0, 0, 0);
        __syncthreads();
    }

    // 32x32 C/D layout: col = lane&31, row = (reg&3) + 8*(reg>>2) + 4*(lane>>5)
    if (ACT) {
        // Fused quant+gelu, pack into act's fragment-order layout via LDS.
        // Phase ph handles mi=ph (rows rb = ph and ph+2), 64 rows x 128 cols
        // = 16 KB in smem.  Compressed row cr = (wave>>1)*32 + rowpat.
        // XOR chunk swizzle ch^= (cr&15): ds_writes 2-way, ds_reads 0-way.
        const int wpair = wave >> 1;
        const size_t tbase = ((size_t)by * (N >> 5) + (size_t)bx * 4) << 9;
        #pragma unroll
        for (int ph = 0; ph < 2; ++ph) {
            __syncthreads();
            #pragma unroll
            for (int ni = 0; ni < 2; ++ni) {
                const int col = wc + ni * 32 + l31;
                #pragma unroll
                for (int r = 0; r < 16; ++r) {
                    const int rowpat = (r & 3) + 8 * (r >> 2) + 4 * lh;
                    const int cr = wpair * 32 + rowpat;
                    float h = acc[ph][ni][r];
                    float q = rintf(h * 10.0f);      // round half-to-even
                    q = fminf(fmaxf(q, -32768.0f), 32767.0f);
                    h = gelu_fast(q * 0.1f);
                    const int ch = (col >> 3) ^ (cr & 15);
                    smem[cr * 128 + ch * 8 + (col & 7)] = (bf16_t)h;
                }
            }
            __syncthreads();
            // Store 1024 chunks (4 ktiles x 256): contiguous dst chunks.
            const int run = tid >> 7;                // rb = ph + 2*run
            const int idx = tid & 127;               // ks*64 + half*32 + rr
            const int ks  = idx >> 6, hf = (idx >> 5) & 1, rr = idx & 31;
            const int cr  = run * 32 + rr;
            const int cb  = (ph + 2 * run) * 128 + idx;
            #pragma unroll
            for (int tt = 0; tt < 4; ++tt) {
                const int gcol = tt * 32 + (2 * ks + hf) * 8;
                const int ch = (gcol >> 3) ^ (cr & 15);
                bf16x8 v = *(const bf16x8*)(smem + cr * 128 + ch * 8);
                *(bf16x8*)((bf16_t*)C + (tbase + (size_t)tt * 512 + cb) * 8) = v;
            }
        }
    } else {
        // Row-major fp32 stores (half-wave writes 128B contiguous).
        const int brow = by * 128, bcol = bx * 128;
        #pragma unroll
        for (int mi = 0; mi < 2; ++mi) {
          #pragma unroll
          for (int ni = 0; ni < 2; ++ni) {
            const int col = bcol + wc + ni * 32 + l31;
            #pragma unroll
            for (int r = 0; r < 16; ++r) {
              const int row = brow + wr + mi * 32 + (r & 3) + 8 * (r >> 2) + 4 * lh;
              C[(size_t)row * N + col] = (OutT)acc[mi][ni][r];
            }
          }
        }
    }
}

extern "C" void kernel_launch(void* const* d_in, const int* in_sizes, int n_in,
                              void* d_out, int out_size, void* d_ws, size_t ws_size,
                              hipStream_t stream)
{
    const int M  = 8192;   // BATCH*SEQ
    const int DM = 2048;   // d_model
    const int DF = 8192;   // d_ff

    const float* x  = (const float*)d_in[0];
    const float* W1 = (const float*)d_in[1];
    const float* W2 = (const float*)d_in[2];
    float* out = (float*)d_out;

    bf16_t* xb  = (bf16_t*)d_ws;                      // packed [M,DM]
    bf16_t* w1b = xb  + (size_t)M  * DM;              // packed [DF,DM]
    bf16_t* w2b = w1b + (size_t)DF * DM;              // packed [DM,DF]
    bf16_t* act = w2b + (size_t)DM * DF;              // packed [M,DF]

    // pack converters: one thread per 16B output chunk
    {
        int nblk = (int)(((size_t)M * DM / 8) / 256);     // 8192
        cvt_pack_bf16<<<nblk, 256, 0, stream>>>(x,  xb,  DM, 6);
        nblk = (int)(((size_t)DF * DM / 8) / 256);        // 8192
        cvt_pack_bf16<<<nblk, 256, 0, stream>>>(W1, w1b, DM, 6);
        nblk = (int)(((size_t)DM * DF / 8) / 256);        // 8192
        cvt_pack_bf16<<<nblk, 256, 0, stream>>>(W2, w2b, DF, 8);
    }

    // GEMM1 + fused quant/gelu: act = pack(gelu_q(xb @ w1b^T))
    gemm_bt<true, bf16_t, false>
        <<<dim3(DF / 128, M / 128), 256, 0, stream>>>(xb, w1b, act, M, DF, DM, 0, 0);
    // GEMM2: out = act @ w2b^T (row-major fp32), XCD-grouped block order
    gemm_bt<false, float, true>
        <<<dim3((DM / 128) * (M / 128), 1), 256, 0, stream>>>(act, w2b, out, M, DM, DF, DM / 128, M / 128);
}